// Round 1
// baseline (10.182 us; speedup 1.0000x reference)
//
#include <hip/hip_runtime.h>

// borders = 1 - (pixel survives 3x cross-erosion in exactly one class)
// Equivalent closed form: border==0 iff the L1-diamond of radius 3 around the
// pixel is fully in-bounds and every label in it equals the center label.

constexpr int NB = 8;
constexpr int H  = 64;
constexpr int W  = 2048;   // 2^11
constexpr int R  = 3;
constexpr int TOTAL = NB * H * W;  // 1,048,576

__global__ __launch_bounds__(256)
void border_kernel(const int* __restrict__ lab, float* __restrict__ out) {
    const int idx = blockIdx.x * 256 + threadIdx.x;   // grid sized exactly
    const int j = idx & (W - 1);
    const int i = (idx >> 11) & (H - 1);

    float border = 1.0f;
    if (i >= R && i < H - R && j >= R && j < W - R) {
        const int* p = lab + idx;
        const int L = p[0];
        bool ok = true;
        #pragma unroll
        for (int di = -R; di <= R; ++di) {
            const int w = R - (di < 0 ? -di : di);
            #pragma unroll
            for (int dj = -w; dj <= w; ++dj) {
                if (di == 0 && dj == 0) continue;
                ok &= (p[di * W + dj] == L);
            }
        }
        border = ok ? 0.0f : 1.0f;
    }
    out[idx] = border;
}

extern "C" void kernel_launch(void* const* d_in, const int* in_sizes, int n_in,
                              void* d_out, int out_size, void* d_ws, size_t ws_size,
                              hipStream_t stream) {
    const int* lab = (const int*)d_in[0];
    float* out = (float*)d_out;
    border_kernel<<<TOTAL / 256, 256, 0, stream>>>(lab, out);
}

// Round 2
// 10.027 us; speedup vs baseline: 1.0155x; 1.0155x over previous
//
#include <hip/hip_runtime.h>

// border[i,j] = 0 iff the L1-diamond of radius 3 around (i,j) is fully
// in-bounds and every label in it equals the center label.
// 4 pixels per thread, int4 halo loads, float4 store.

constexpr int NB = 8;
constexpr int H  = 64;
constexpr int W  = 2048;   // 2^11
constexpr int R  = 3;
constexpr int TOTAL = NB * H * W;      // 1,048,576 pixels
constexpr int NT    = TOTAL / 4;       // 262,144 threads

__global__ __launch_bounds__(256)
void border4_kernel(const int* __restrict__ lab, float* __restrict__ out) {
    const int t   = blockIdx.x * 256 + threadIdx.x;
    const int idx = t << 2;                 // first of 4 consecutive pixels
    const int j0  = idx & (W - 1);
    const int i   = (idx >> 11) & (H - 1);
    const int* p  = lab + idx;

    float rr[4];

    if (i >= R && i < H - R && j0 >= 4 && j0 <= W - 8) {
        // ---- fast interior path: whole 4-pixel block has full halo ----
        int w[5][12];                       // rows di=-2..2, cols j0-4 .. j0+7
        #pragma unroll
        for (int d = 0; d < 5; ++d) {
            const int di = d - 2;
            const int4 a = *(const int4*)(p + di * W - 4);
            const int4 b = *(const int4*)(p + di * W);
            const int4 c = *(const int4*)(p + di * W + 4);
            w[d][0] = a.x; w[d][1]  = a.y; w[d][2]  = a.z; w[d][3]  = a.w;
            w[d][4] = b.x; w[d][5]  = b.y; w[d][6]  = b.z; w[d][7]  = b.w;
            w[d][8] = c.x; w[d][9]  = c.y; w[d][10] = c.z; w[d][11] = c.w;
        }
        const int4 up = *(const int4*)(p - 3 * W);
        const int4 dn = *(const int4*)(p + 3 * W);
        const int u4[4] = {up.x, up.y, up.z, up.w};
        const int d4[4] = {dn.x, dn.y, dn.z, dn.w};

        #pragma unroll
        for (int k = 0; k < 4; ++k) {
            const int L = w[2][4 + k];
            bool ok = (u4[k] == L) & (d4[k] == L);
            #pragma unroll
            for (int d = 0; d < 5; ++d) {
                const int di = d - 2;
                const int hw = 3 - (di < 0 ? -di : di);
                #pragma unroll
                for (int dj = -hw; dj <= hw; ++dj) {
                    if (di == 0 && dj == 0) continue;
                    ok &= (w[d][4 + k + dj] == L);
                }
            }
            rr[k] = ok ? 0.0f : 1.0f;
        }
    } else {
        // ---- edge path: per-pixel guarded (only ~1.5% of threads) ----
        #pragma unroll
        for (int k = 0; k < 4; ++k) {
            const int j = j0 + k;
            float border = 1.0f;
            if (i >= R && i < H - R && j >= R && j < W - R) {
                const int* q = p + k;
                const int L = q[0];
                bool ok = true;
                #pragma unroll
                for (int di = -R; di <= R; ++di) {
                    const int hw = R - (di < 0 ? -di : di);
                    #pragma unroll
                    for (int dj = -hw; dj <= hw; ++dj) {
                        if (di == 0 && dj == 0) continue;
                        ok &= (q[di * W + dj] == L);
                    }
                }
                border = ok ? 0.0f : 1.0f;
            }
            rr[k] = border;
        }
    }

    *(float4*)(out + idx) = make_float4(rr[0], rr[1], rr[2], rr[3]);
}

extern "C" void kernel_launch(void* const* d_in, const int* in_sizes, int n_in,
                              void* d_out, int out_size, void* d_ws, size_t ws_size,
                              hipStream_t stream) {
    const int* lab = (const int*)d_in[0];
    float* out = (float*)d_out;
    border4_kernel<<<NT / 256, 256, 0, stream>>>(lab, out);
}